// Round 16
// baseline (99.926 us; speedup 1.0000x reference)
//
#include <hip/hip_runtime.h>

// Path signature, depth 4: B=32, L=1024, d=8, fp32.
// Levels: S1(8) S2(64) S3(512) S4(4096); sig stride 4680 floats.
//
// R16 = R15 (best, 93.4us) rebalanced + chunk software pipeline.
//  sig_chunk64: 512 blocks (32 batches x 16 chunks), 4 k-slice q-waves;
//    chunk = 64 increments, 65 path rows (2.1KB) staged in LDS; next row
//    PREFETCHED into registers one step ahead (hides ~120cyc ds_read latency
//    behind ~130cyc VALU). 2 waves/SIMD adds TLP.
//  sig_fold16: 32 blocks x 256 threads - R9's proven staged_folds shape,
//    nsig=16 (15 sequential folds), writes d_out.
// Lessons: (R2) no full unroll of fold loops; (R3/R12/R14) fold kernels
// outside the R9 shape (256 thr, sequential staged_folds, small prefetch) get
// VGPR-collapsed (76/76/36) and serialize; (R8) no +4 LDS padding; (R11)
// agent-scope grid barriers ~30us each; (R10-R15) floor ~53us harness +
// ~12-18us per dispatch boundary; (R15) coarser leaves beat merged kernels.

#define D 8
#define LPATH 1024
#define BATCH 32
#define NCHUNK 16
#define MSTEP 64
#define SIG_STRIDE 4680
#define OFF2 8
#define OFF3 72
#define OFF4 584
#define N13F4 146  // 584 floats of levels 1-3 = 146 float4s

__device__ __forceinline__ void load8(const float* __restrict__ p, float* dst) {
  float4 lo = *(const float4*)p;
  float4 hi = *(const float4*)(p + 4);
  dst[0] = lo.x; dst[1] = lo.y; dst[2] = lo.z; dst[3] = lo.w;
  dst[4] = hi.x; dst[5] = hi.y; dst[6] = hi.z; dst[7] = hi.w;
}

__device__ __forceinline__ void store8(float* __restrict__ p, const float* src) {
  *(float4*)p       = make_float4(src[0], src[1], src[2], src[3]);
  *(float4*)(p + 4) = make_float4(src[4], src[5], src[6], src[7]);
}

// ------ Kernel 1: one block per 64-inc chunk; path in LDS, row prefetch -----
__global__ __launch_bounds__(256) void sig_chunk64(const float* __restrict__ path,
                                                   float* __restrict__ ws) {
  __shared__ alignas(16) float lp[65 * D];  // 2.08 KB

  const int tid  = threadIdx.x;
  const int lane = tid & 63;
  const int q    = tid >> 6;                // k-slice wave 0..3
  const int b = blockIdx.x >> 4;            // batch
  const int c = blockIdx.x & (NCHUNK - 1);  // chunk
  const int i = lane >> 3;
  const int j = lane & 7;
  const int k0 = q * 2;

  const int g0 = c * MSTEP;
  const int nrows = (65 < LPATH - g0) ? 65 : (LPATH - g0);
  const int nf4 = nrows * 2;  // <= 130
  const float* __restrict__ bp = path + (size_t)b * (LPATH * D) + (size_t)g0 * D;

  if (tid < nf4) *(float4*)&lp[4 * tid] = *(const float4*)(bp + 4 * tid);
  __syncthreads();

  // current row (cm) and prefetched next row (nmA)
  float cm[D];
  *(float4*)&cm[0] = *(const float4*)&lp[0];
  *(float4*)&cm[4] = *(const float4*)&lp[4];
  float cwi = lp[i], cwj = lp[j];

  int r1 = (1 < nrows) ? 1 : (nrows - 1);
  float nmA[D];
  *(float4*)&nmA[0] = *(const float4*)&lp[r1 * D];
  *(float4*)&nmA[4] = *(const float4*)&lp[r1 * D + 4];
  float nwiA = lp[r1 * D + i], nwjA = lp[r1 * D + j];

  float s1 = 0.f, s2 = 0.f;
  float s3[D] = {0.f, 0.f, 0.f, 0.f, 0.f, 0.f, 0.f, 0.f};
  float s4[2][D];
#pragma unroll
  for (int t = 0; t < 2; ++t)
#pragma unroll
    for (int m = 0; m < D; ++m) s4[t][m] = 0.f;

#pragma unroll 1
  for (int t = 0; t < MSTEP; ++t) {
    // issue prefetch of row t+2 (registers) before the compute of row t+1
    int rn = t + 2;
    rn = rn < nrows ? rn : nrows - 1;  // clamp -> zero-increment pad
    float nmB[D];
    *(float4*)&nmB[0] = *(const float4*)&lp[rn * D];
    *(float4*)&nmB[4] = *(const float4*)&lp[rn * D + 4];
    float nwiB = lp[rn * D + i], nwjB = lp[rn * D + j];

    float wm[D];
#pragma unroll
    for (int m = 0; m < D; ++m) wm[m] = nmA[m] - cm[m];
    float wi = nwiA - cwi, wj = nwjA - cwj;

    // level-4 slice: S4 += S3(x)w + S2(x)w^2/2 + S1(x)w^3/6 + w^4/24 (Horner)
    float h1  = __builtin_fmaf(wi, 0.25f, s1);
    float h2  = __builtin_fmaf(h1, wj * (1.f / 3.f), s2);
    float hb2 = h2 * 0.5f;
    float b3a = __builtin_fmaf(hb2, wm[k0], s3[k0]);
    float b3b = __builtin_fmaf(hb2, wm[k0 + 1], s3[k0 + 1]);
#pragma unroll
    for (int m = 0; m < D; ++m) s4[0][m] = __builtin_fmaf(b3a, wm[m], s4[0][m]);
#pragma unroll
    for (int m = 0; m < D; ++m) s4[1][m] = __builtin_fmaf(b3b, wm[m], s4[1][m]);

    // level 3 (full, replicated across q-waves)
    float c1 = __builtin_fmaf(wi, (1.f / 3.f), s1);
    float c2 = __builtin_fmaf(c1, wj * 0.5f, s2);
#pragma unroll
    for (int k = 0; k < D; ++k) s3[k] = __builtin_fmaf(c2, wm[k], s3[k]);

    // levels 2, 1
    float d1 = __builtin_fmaf(wi, 0.5f, s1);
    s2 = __builtin_fmaf(d1, wj, s2);
    s1 += wi;

    // rotate row pipeline
#pragma unroll
    for (int m = 0; m < D; ++m) { cm[m] = nmA[m]; nmA[m] = nmB[m]; }
    cwi = nwiA; cwj = nwjA; nwiA = nwiB; nwjA = nwjB;
  }

  float* __restrict__ slot = ws + (size_t)(b * NCHUNK + c) * SIG_STRIDE;
  store8(slot + OFF4 + lane * 64 + k0 * 8, s4[0]);
  store8(slot + OFF4 + lane * 64 + (k0 + 1) * 8, s4[1]);
  if (q == 0) {
    if (j == 0) slot[i] = s1;
    slot[OFF2 + lane] = s2;
    store8(slot + OFF3 + lane * 8, s3);
  }
}

// ---- fold from LDS levels1-3 + register B4 slice (k-sliced Chen product) ---
__device__ __forceinline__ void fold_lds(const float* __restrict__ L,
                                         const float b4[2][D], float& s1,
                                         float& s2, float s3[D], float s4[2][D],
                                         int i, int j, int lane, int k0) {
  float b1i = L[i];
  float b1j = L[j];
  float sb1[D];
#pragma unroll
  for (int m = 0; m < D; ++m) sb1[m] = L[m];
  float b2own = L[OFF2 + lane];
  float b2row[D], b3own[D];
  *(float4*)&b2row[0] = *(const float4*)&L[OFF2 + j * 8];
  *(float4*)&b2row[4] = *(const float4*)&L[OFF2 + j * 8 + 4];
  *(float4*)&b3own[0] = *(const float4*)&L[OFF3 + lane * 8];
  *(float4*)&b3own[4] = *(const float4*)&L[OFF3 + lane * 8 + 4];

  // C4 = A4 + B4 + A3[i,j,k]B1[m] + A2[i,j]B2[k,m] + A1[i]B3[j,k,m]
#pragma unroll
  for (int t = 0; t < 2; ++t) {
    const int k = k0 + t;
    float b2k[D], b3k[D];
    *(float4*)&b2k[0] = *(const float4*)&L[OFF2 + k * 8];
    *(float4*)&b2k[4] = *(const float4*)&L[OFF2 + k * 8 + 4];
    *(float4*)&b3k[0] = *(const float4*)&L[OFF3 + (j * 8 + k) * 8];
    *(float4*)&b3k[4] = *(const float4*)&L[OFF3 + (j * 8 + k) * 8 + 4];
    float a3k = s3[k];
#pragma unroll
    for (int m = 0; m < D; ++m) {
      float v = __builtin_fmaf(a3k, sb1[m], s4[t][m] + b4[t][m]);
      v = __builtin_fmaf(s2, b2k[m], v);
      s4[t][m] = __builtin_fmaf(s1, b3k[m], v);
    }
  }
  // C3 = A3 + B3 + A1[i]B2[j,k] + A2[i,j]B1[k]
#pragma unroll
  for (int k = 0; k < D; ++k) {
    float v = __builtin_fmaf(s1, b2row[k], s3[k] + b3own[k]);
    s3[k] = __builtin_fmaf(s2, sb1[k], v);
  }
  s2 = s2 + b2own + s1 * b1j;
  s1 = s1 + b1i;
}

// Init state from sig0 at base, fold sigs 1..nsig-1. One sync per fold.
// (R9 verbatim - the only fold shape that keeps sane VGPR allocation.)
__device__ __forceinline__ void staged_folds(const float* __restrict__ base,
                                             int nsig, float (*lds13)[592],
                                             int tid, int i, int j, int lane,
                                             int k0, float& s1, float& s2,
                                             float s3[D], float s4[2][D]) {
  s1 = base[i];
  s2 = base[OFF2 + lane];
  load8(base + OFF3 + lane * 8, s3);
  load8(base + OFF4 + lane * 64 + k0 * 8, s4[0]);
  load8(base + OFF4 + lane * 64 + (k0 + 1) * 8, s4[1]);

  const float* __restrict__ B1p = base + (size_t)SIG_STRIDE;
  float b4cur[2][D];
  load8(B1p + OFF4 + lane * 64 + k0 * 8, b4cur[0]);
  load8(B1p + OFF4 + lane * 64 + (k0 + 1) * 8, b4cur[1]);
  if (tid < N13F4) {
    float4 sv = *(const float4*)(B1p + tid * 4);
    *(float4*)&lds13[1][tid * 4] = sv;
  }
  __syncthreads();

#pragma unroll 1
  for (int c = 1; c < nsig; ++c) {
    const bool more = (c + 1 < nsig);
    const float* __restrict__ Bn = base + (size_t)(c + 1) * SIG_STRIDE;
    float4 svn;
    float b4n[2][D];
    if (more) {
      if (tid < N13F4) svn = *(const float4*)(Bn + tid * 4);
      load8(Bn + OFF4 + lane * 64 + k0 * 8, b4n[0]);
      load8(Bn + OFF4 + lane * 64 + (k0 + 1) * 8, b4n[1]);
    }

    fold_lds(lds13[c & 1], b4cur, s1, s2, s3, s4, i, j, lane, k0);

    if (more) {
      if (tid < N13F4) *(float4*)&lds13[(c + 1) & 1][tid * 4] = svn;
#pragma unroll
      for (int t = 0; t < 2; ++t)
#pragma unroll
        for (int m = 0; m < D; ++m) b4cur[t][m] = b4n[t][m];
    }
    __syncthreads();
  }
}

// ------ Kernel 2: block bb folds the 16 chunk sigs of batch bb -> d_out -----
__global__ __launch_bounds__(256) void sig_fold16(const float* __restrict__ ws,
                                                  float* __restrict__ out) {
  __shared__ alignas(16) float lds13[2][592];
  const int tid  = threadIdx.x;
  const int q    = tid >> 6;  // k-slice wave 0..3
  const int lane = tid & 63;
  const int bb = blockIdx.x;
  const int i = lane >> 3;
  const int j = lane & 7;
  const int k0 = q * 2;

  const float* __restrict__ base = ws + (size_t)bb * NCHUNK * SIG_STRIDE;

  float s1, s2, s3[D], s4[2][D];
  staged_folds(base, NCHUNK, lds13, tid, i, j, lane, k0, s1, s2, s3, s4);

  // d_out: S1 (32x8) | S2 (32x64) | S3 (32x512) | S4 (32x4096)
  if (q == 0) {
    if (j == 0) out[bb * 8 + i] = s1;
    out[256 + bb * 64 + lane] = s2;
    store8(out + 2304 + bb * 512 + lane * 8, s3);
  }
  store8(out + 18688 + bb * 4096 + lane * 64 + k0 * 8, s4[0]);
  store8(out + 18688 + bb * 4096 + lane * 64 + (k0 + 1) * 8, s4[1]);
}

extern "C" void kernel_launch(void* const* d_in, const int* in_sizes, int n_in,
                              void* d_out, int out_size, void* d_ws, size_t ws_size,
                              hipStream_t stream) {
  const float* path = (const float*)d_in[0];
  // d_in[1] = depth (==4), compile-time specialized.
  float* out = (float*)d_out;
  float* ws  = (float*)d_ws;  // 32*16*4680*4 = 9.6 MB used

  // 32 batches x 16 chunks = 512 blocks (4 q-waves each), 64 incs per chunk
  sig_chunk64<<<dim3(512), dim3(256), 0, stream>>>(path, ws);
  // 32 batches = 32 blocks; R9-shape staged fold over 16 sigs
  sig_fold16<<<dim3(BATCH), dim3(256), 0, stream>>>(ws, out);
}

// Round 17
// 97.468 us; speedup vs baseline: 1.0252x; 1.0252x over previous
//
#include <hip/hip_runtime.h>

// Path signature, depth 4: B=32, L=1024, d=8, fp32.
// Levels: S1(8) S2(64) S3(512) S4(4096); sig stride 4680 floats.
//
// R17 = R15 (best, 93.4us) + register row-prefetch in sig_chunk128 ONLY.
//  sig_chunk128: 256 blocks (32 batches x 8 chunks), 4 k-slice q-waves;
//    chunk = 128 increments, 129 path rows (4.1KB) in LDS; row t+2
//    prefetched into registers while computing with row t+1 (hides the
//    ~120cyc ds_read chain behind ~130cyc of VALU; 1 wave/SIMD = no TLP,
//    so ILP is the only latency hiding available).
//  sig_fold8f: R15 verbatim - 32 blocks x 256 threads, R9-shape staged_folds
//    over 8 sigs (7 folds; R16 proved more folds = worse: each fold pays a
//    serial sync+stage latency).
// Lessons: (R2) no full unroll of fold loops; (R3/R12/R14) fold kernels
// outside the R9 shape get VGPR-collapsed (76/76/36) and serialize; (R8) no
// +4 LDS padding; (R11) agent-scope grid barriers ~30us; (R10-R16) floor
// ~53us harness + ~12-18us per dispatch boundary; (R15/R16) 128-inc leaves +
// 7 folds is the right leaf/fold balance.

#define D 8
#define LPATH 1024
#define BATCH 32
#define NCHUNK 8
#define MSTEP 128
#define SIG_STRIDE 4680
#define OFF2 8
#define OFF3 72
#define OFF4 584
#define N13F4 146  // 584 floats of levels 1-3 = 146 float4s

__device__ __forceinline__ void load8(const float* __restrict__ p, float* dst) {
  float4 lo = *(const float4*)p;
  float4 hi = *(const float4*)(p + 4);
  dst[0] = lo.x; dst[1] = lo.y; dst[2] = lo.z; dst[3] = lo.w;
  dst[4] = hi.x; dst[5] = hi.y; dst[6] = hi.z; dst[7] = hi.w;
}

__device__ __forceinline__ void store8(float* __restrict__ p, const float* src) {
  *(float4*)p       = make_float4(src[0], src[1], src[2], src[3]);
  *(float4*)(p + 4) = make_float4(src[4], src[5], src[6], src[7]);
}

// ------ Kernel 1: one block per 128-inc chunk; LDS path + row prefetch ------
__global__ __launch_bounds__(256) void sig_chunk128(const float* __restrict__ path,
                                                    float* __restrict__ ws) {
  __shared__ alignas(16) float lp[129 * D];  // 4.13 KB

  const int tid  = threadIdx.x;
  const int lane = tid & 63;
  const int q    = tid >> 6;                // k-slice wave 0..3
  const int b = blockIdx.x >> 3;            // batch
  const int c = blockIdx.x & (NCHUNK - 1);  // chunk
  const int i = lane >> 3;
  const int j = lane & 7;
  const int k0 = q * 2;

  const int g0 = c * MSTEP;
  const int nrows = (129 < LPATH - g0) ? 129 : (LPATH - g0);
  const int nf4 = nrows * 2;
  const float* __restrict__ bp = path + (size_t)b * (LPATH * D) + (size_t)g0 * D;

#pragma unroll
  for (int it = 0; it < 2; ++it) {
    int n = tid + it * 256;
    if (n < nf4) *(float4*)&lp[4 * n] = *(const float4*)(bp + 4 * n);
  }
  __syncthreads();

  // row pipeline: cm = row t, nmA = row t+1 (prefetched)
  float cm[D];
  *(float4*)&cm[0] = *(const float4*)&lp[0];
  *(float4*)&cm[4] = *(const float4*)&lp[4];
  float cwi = lp[i], cwj = lp[j];

  const int r1 = (1 < nrows) ? 1 : (nrows - 1);
  float nmA[D];
  *(float4*)&nmA[0] = *(const float4*)&lp[r1 * D];
  *(float4*)&nmA[4] = *(const float4*)&lp[r1 * D + 4];
  float nwiA = lp[r1 * D + i], nwjA = lp[r1 * D + j];

  float s1 = 0.f, s2 = 0.f;
  float s3[D] = {0.f, 0.f, 0.f, 0.f, 0.f, 0.f, 0.f, 0.f};
  float s4[2][D];
#pragma unroll
  for (int t = 0; t < 2; ++t)
#pragma unroll
    for (int m = 0; m < D; ++m) s4[t][m] = 0.f;

#pragma unroll 1
  for (int t = 0; t < MSTEP; ++t) {
    // issue ds_reads for row t+2 BEFORE computing with row t+1
    int rn = t + 2;
    rn = rn < nrows ? rn : nrows - 1;  // clamp -> zero-increment pad
    float nmB[D];
    *(float4*)&nmB[0] = *(const float4*)&lp[rn * D];
    *(float4*)&nmB[4] = *(const float4*)&lp[rn * D + 4];
    float nwiB = lp[rn * D + i], nwjB = lp[rn * D + j];

    float wm[D];
#pragma unroll
    for (int m = 0; m < D; ++m) wm[m] = nmA[m] - cm[m];
    float wi = nwiA - cwi, wj = nwjA - cwj;

    // level-4 slice: S4 += S3(x)w + S2(x)w^2/2 + S1(x)w^3/6 + w^4/24 (Horner)
    float h1  = __builtin_fmaf(wi, 0.25f, s1);
    float h2  = __builtin_fmaf(h1, wj * (1.f / 3.f), s2);
    float hb2 = h2 * 0.5f;
    float b3a = __builtin_fmaf(hb2, wm[k0], s3[k0]);
    float b3b = __builtin_fmaf(hb2, wm[k0 + 1], s3[k0 + 1]);
#pragma unroll
    for (int m = 0; m < D; ++m) s4[0][m] = __builtin_fmaf(b3a, wm[m], s4[0][m]);
#pragma unroll
    for (int m = 0; m < D; ++m) s4[1][m] = __builtin_fmaf(b3b, wm[m], s4[1][m]);

    // level 3 (full, replicated across q-waves)
    float c1 = __builtin_fmaf(wi, (1.f / 3.f), s1);
    float c2 = __builtin_fmaf(c1, wj * 0.5f, s2);
#pragma unroll
    for (int k = 0; k < D; ++k) s3[k] = __builtin_fmaf(c2, wm[k], s3[k]);

    // levels 2, 1
    float d1 = __builtin_fmaf(wi, 0.5f, s1);
    s2 = __builtin_fmaf(d1, wj, s2);
    s1 += wi;

    // rotate pipeline registers
#pragma unroll
    for (int m = 0; m < D; ++m) { cm[m] = nmA[m]; nmA[m] = nmB[m]; }
    cwi = nwiA; cwj = nwjA; nwiA = nwiB; nwjA = nwjB;
  }

  float* __restrict__ slot = ws + (size_t)(b * NCHUNK + c) * SIG_STRIDE;
  store8(slot + OFF4 + lane * 64 + k0 * 8, s4[0]);
  store8(slot + OFF4 + lane * 64 + (k0 + 1) * 8, s4[1]);
  if (q == 0) {
    if (j == 0) slot[i] = s1;
    slot[OFF2 + lane] = s2;
    store8(slot + OFF3 + lane * 8, s3);
  }
}

// ---- fold from LDS levels1-3 + register B4 slice (k-sliced Chen product) ---
__device__ __forceinline__ void fold_lds(const float* __restrict__ L,
                                         const float b4[2][D], float& s1,
                                         float& s2, float s3[D], float s4[2][D],
                                         int i, int j, int lane, int k0) {
  float b1i = L[i];
  float b1j = L[j];
  float sb1[D];
#pragma unroll
  for (int m = 0; m < D; ++m) sb1[m] = L[m];
  float b2own = L[OFF2 + lane];
  float b2row[D], b3own[D];
  *(float4*)&b2row[0] = *(const float4*)&L[OFF2 + j * 8];
  *(float4*)&b2row[4] = *(const float4*)&L[OFF2 + j * 8 + 4];
  *(float4*)&b3own[0] = *(const float4*)&L[OFF3 + lane * 8];
  *(float4*)&b3own[4] = *(const float4*)&L[OFF3 + lane * 8 + 4];

  // C4 = A4 + B4 + A3[i,j,k]B1[m] + A2[i,j]B2[k,m] + A1[i]B3[j,k,m]
#pragma unroll
  for (int t = 0; t < 2; ++t) {
    const int k = k0 + t;
    float b2k[D], b3k[D];
    *(float4*)&b2k[0] = *(const float4*)&L[OFF2 + k * 8];
    *(float4*)&b2k[4] = *(const float4*)&L[OFF2 + k * 8 + 4];
    *(float4*)&b3k[0] = *(const float4*)&L[OFF3 + (j * 8 + k) * 8];
    *(float4*)&b3k[4] = *(const float4*)&L[OFF3 + (j * 8 + k) * 8 + 4];
    float a3k = s3[k];
#pragma unroll
    for (int m = 0; m < D; ++m) {
      float v = __builtin_fmaf(a3k, sb1[m], s4[t][m] + b4[t][m]);
      v = __builtin_fmaf(s2, b2k[m], v);
      s4[t][m] = __builtin_fmaf(s1, b3k[m], v);
    }
  }
  // C3 = A3 + B3 + A1[i]B2[j,k] + A2[i,j]B1[k]
#pragma unroll
  for (int k = 0; k < D; ++k) {
    float v = __builtin_fmaf(s1, b2row[k], s3[k] + b3own[k]);
    s3[k] = __builtin_fmaf(s2, sb1[k], v);
  }
  s2 = s2 + b2own + s1 * b1j;
  s1 = s1 + b1i;
}

// Init state from sig0 at base, fold sigs 1..nsig-1. One sync per fold.
// (R9 verbatim - the only fold shape that keeps sane VGPR allocation.)
__device__ __forceinline__ void staged_folds(const float* __restrict__ base,
                                             int nsig, float (*lds13)[592],
                                             int tid, int i, int j, int lane,
                                             int k0, float& s1, float& s2,
                                             float s3[D], float s4[2][D]) {
  s1 = base[i];
  s2 = base[OFF2 + lane];
  load8(base + OFF3 + lane * 8, s3);
  load8(base + OFF4 + lane * 64 + k0 * 8, s4[0]);
  load8(base + OFF4 + lane * 64 + (k0 + 1) * 8, s4[1]);

  const float* __restrict__ B1p = base + (size_t)SIG_STRIDE;
  float b4cur[2][D];
  load8(B1p + OFF4 + lane * 64 + k0 * 8, b4cur[0]);
  load8(B1p + OFF4 + lane * 64 + (k0 + 1) * 8, b4cur[1]);
  if (tid < N13F4) {
    float4 sv = *(const float4*)(B1p + tid * 4);
    *(float4*)&lds13[1][tid * 4] = sv;
  }
  __syncthreads();

#pragma unroll 1
  for (int c = 1; c < nsig; ++c) {
    const bool more = (c + 1 < nsig);
    const float* __restrict__ Bn = base + (size_t)(c + 1) * SIG_STRIDE;
    float4 svn;
    float b4n[2][D];
    if (more) {
      if (tid < N13F4) svn = *(const float4*)(Bn + tid * 4);
      load8(Bn + OFF4 + lane * 64 + k0 * 8, b4n[0]);
      load8(Bn + OFF4 + lane * 64 + (k0 + 1) * 8, b4n[1]);
    }

    fold_lds(lds13[c & 1], b4cur, s1, s2, s3, s4, i, j, lane, k0);

    if (more) {
      if (tid < N13F4) *(float4*)&lds13[(c + 1) & 1][tid * 4] = svn;
#pragma unroll
      for (int t = 0; t < 2; ++t)
#pragma unroll
        for (int m = 0; m < D; ++m) b4cur[t][m] = b4n[t][m];
    }
    __syncthreads();
  }
}

// ------ Kernel 2: block bb folds the 8 chunk sigs of batch bb -> d_out ------
__global__ __launch_bounds__(256) void sig_fold8f(const float* __restrict__ ws,
                                                  float* __restrict__ out) {
  __shared__ alignas(16) float lds13[2][592];
  const int tid  = threadIdx.x;
  const int q    = tid >> 6;  // k-slice wave 0..3
  const int lane = tid & 63;
  const int bb = blockIdx.x;
  const int i = lane >> 3;
  const int j = lane & 7;
  const int k0 = q * 2;

  const float* __restrict__ base = ws + (size_t)bb * NCHUNK * SIG_STRIDE;

  float s1, s2, s3[D], s4[2][D];
  staged_folds(base, NCHUNK, lds13, tid, i, j, lane, k0, s1, s2, s3, s4);

  // d_out: S1 (32x8) | S2 (32x64) | S3 (32x512) | S4 (32x4096)
  if (q == 0) {
    if (j == 0) out[bb * 8 + i] = s1;
    out[256 + bb * 64 + lane] = s2;
    store8(out + 2304 + bb * 512 + lane * 8, s3);
  }
  store8(out + 18688 + bb * 4096 + lane * 64 + k0 * 8, s4[0]);
  store8(out + 18688 + bb * 4096 + lane * 64 + (k0 + 1) * 8, s4[1]);
}

extern "C" void kernel_launch(void* const* d_in, const int* in_sizes, int n_in,
                              void* d_out, int out_size, void* d_ws, size_t ws_size,
                              hipStream_t stream) {
  const float* path = (const float*)d_in[0];
  // d_in[1] = depth (==4), compile-time specialized.
  float* out = (float*)d_out;
  float* ws  = (float*)d_ws;  // 32*8*4680*4 = 4.8 MB used

  // 32 batches x 8 chunks = 256 blocks (4 q-waves each), 128 incs per chunk
  sig_chunk128<<<dim3(256), dim3(256), 0, stream>>>(path, ws);
  // 32 batches = 32 blocks; R9-shape staged fold over 8 sigs
  sig_fold8f<<<dim3(BATCH), dim3(256), 0, stream>>>(ws, out);
}

// Round 18
// 93.081 us; speedup vs baseline: 1.0735x; 1.0471x over previous
//
#include <hip/hip_runtime.h>

// Path signature, depth 4: B=32, L=1024, d=8, fp32.
// Levels: S1(8) S2(64) S3(512) S4(4096); sig stride 4680 floats.
//
// R18 = R15 verbatim (measured optimum, 93.4us). Every structural and micro
// variant tried in R0-R17 measured worse:
//   - 3 dispatches (R10): 97.2 (extra ~12us dispatch gap)
//   - 1 dispatch + agent-scope grid barriers (R7/R11): 133-134 (each barrier
//     ~30us of L2 writeback/invalidate across 8 XCDs)
//   - merged 31-deep fold (R5), full-state tree (R12), k-sliced tree (R14):
//     fold kernels outside the R9 shape (256 thr, sequential staged_folds,
//     <=24-reg prefetch) get VGPR-collapsed (76/76/36) and serialize
//   - finer leaves 64x16 (R16): +6.5us (folds pay serial sync+stage latency)
//   - register row-prefetch in chunk (R16/R17): +4-6us (rotate overhead on an
//     issue-bound loop; ds_read latency was already compiler-overlapped)
// Budget at 93.4us: ~53us harness poison-fill floor + ~12-15us dispatch gap +
// ~10us kernels (serial-latency-bound, VALUBusy ~5%, HBM ~3%) + tails.
//
// Structure:
//  sig_chunk128: 256 blocks (32 batches x 8 chunks), 4 k-slice q-waves each;
//    chunk = 128 increments, 129 path rows (4.1KB) staged in LDS once, then
//    broadcast ds_reads per step. Wave q owns S4[.][.][2q,2q+1][.] (16 regs)
//    + replicated S1,S2,S3 (10 regs) - identical arithmetic in all q-waves,
//    zero inter-wave communication.
//  sig_fold8f: 32 blocks x 256 threads; sequential Chen fold over the 8
//    chunk sigs: levels1-3 of the next sig double-buffered in 2.3KB LDS
//    (1 float4/thread), B4 k-slice prefetched in 16 VGPRs, one sync/fold.

#define D 8
#define LPATH 1024
#define BATCH 32
#define NCHUNK 8
#define MSTEP 128
#define SIG_STRIDE 4680
#define OFF2 8
#define OFF3 72
#define OFF4 584
#define N13F4 146  // 584 floats of levels 1-3 = 146 float4s

__device__ __forceinline__ void load8(const float* __restrict__ p, float* dst) {
  float4 lo = *(const float4*)p;
  float4 hi = *(const float4*)(p + 4);
  dst[0] = lo.x; dst[1] = lo.y; dst[2] = lo.z; dst[3] = lo.w;
  dst[4] = hi.x; dst[5] = hi.y; dst[6] = hi.z; dst[7] = hi.w;
}

__device__ __forceinline__ void store8(float* __restrict__ p, const float* src) {
  *(float4*)p       = make_float4(src[0], src[1], src[2], src[3]);
  *(float4*)(p + 4) = make_float4(src[4], src[5], src[6], src[7]);
}

// ------ Kernel 1: one block per 128-inc chunk; path staged via LDS ----------
__global__ __launch_bounds__(256) void sig_chunk128(const float* __restrict__ path,
                                                    float* __restrict__ ws) {
  __shared__ alignas(16) float lp[129 * D];  // 4.13 KB

  const int tid  = threadIdx.x;
  const int lane = tid & 63;
  const int q    = tid >> 6;                // k-slice wave 0..3
  const int b = blockIdx.x >> 3;            // batch
  const int c = blockIdx.x & (NCHUNK - 1);  // chunk
  const int i = lane >> 3;
  const int j = lane & 7;
  const int k0 = q * 2;

  const int g0 = c * MSTEP;
  const int nrows = (129 < LPATH - g0) ? 129 : (LPATH - g0);
  const int nf4 = nrows * 2;
  const float* __restrict__ bp = path + (size_t)b * (LPATH * D) + (size_t)g0 * D;

#pragma unroll
  for (int it = 0; it < 2; ++it) {
    int n = tid + it * 256;
    if (n < nf4) *(float4*)&lp[4 * n] = *(const float4*)(bp + 4 * n);
  }
  __syncthreads();

  float cm[D];
  *(float4*)&cm[0] = *(const float4*)&lp[0];
  *(float4*)&cm[4] = *(const float4*)&lp[4];
  float cwi = lp[i], cwj = lp[j];

  float s1 = 0.f, s2 = 0.f;
  float s3[D] = {0.f, 0.f, 0.f, 0.f, 0.f, 0.f, 0.f, 0.f};
  float s4[2][D];
#pragma unroll
  for (int t = 0; t < 2; ++t)
#pragma unroll
    for (int m = 0; m < D; ++m) s4[t][m] = 0.f;

#pragma unroll 1
  for (int t = 0; t < MSTEP; ++t) {
    int rc = t + 1;
    rc = rc < nrows ? rc : nrows - 1;  // clamp -> zero-increment pad
    float nm[D];
    *(float4*)&nm[0] = *(const float4*)&lp[rc * D];
    *(float4*)&nm[4] = *(const float4*)&lp[rc * D + 4];
    float nwi = lp[rc * D + i];
    float nwj = lp[rc * D + j];

    float wm[D];
#pragma unroll
    for (int m = 0; m < D; ++m) wm[m] = nm[m] - cm[m];
    float wi = nwi - cwi, wj = nwj - cwj;

    // level-4 slice: S4 += S3(x)w + S2(x)w^2/2 + S1(x)w^3/6 + w^4/24 (Horner)
    float h1  = __builtin_fmaf(wi, 0.25f, s1);
    float h2  = __builtin_fmaf(h1, wj * (1.f / 3.f), s2);
    float hb2 = h2 * 0.5f;
    float b3a = __builtin_fmaf(hb2, wm[k0], s3[k0]);
    float b3b = __builtin_fmaf(hb2, wm[k0 + 1], s3[k0 + 1]);
#pragma unroll
    for (int m = 0; m < D; ++m) s4[0][m] = __builtin_fmaf(b3a, wm[m], s4[0][m]);
#pragma unroll
    for (int m = 0; m < D; ++m) s4[1][m] = __builtin_fmaf(b3b, wm[m], s4[1][m]);

    // level 3 (full, replicated across q-waves)
    float c1 = __builtin_fmaf(wi, (1.f / 3.f), s1);
    float c2 = __builtin_fmaf(c1, wj * 0.5f, s2);
#pragma unroll
    for (int k = 0; k < D; ++k) s3[k] = __builtin_fmaf(c2, wm[k], s3[k]);

    // levels 2, 1
    float d1 = __builtin_fmaf(wi, 0.5f, s1);
    s2 = __builtin_fmaf(d1, wj, s2);
    s1 += wi;

#pragma unroll
    for (int m = 0; m < D; ++m) cm[m] = nm[m];
    cwi = nwi; cwj = nwj;
  }

  float* __restrict__ slot = ws + (size_t)(b * NCHUNK + c) * SIG_STRIDE;
  store8(slot + OFF4 + lane * 64 + k0 * 8, s4[0]);
  store8(slot + OFF4 + lane * 64 + (k0 + 1) * 8, s4[1]);
  if (q == 0) {
    if (j == 0) slot[i] = s1;
    slot[OFF2 + lane] = s2;
    store8(slot + OFF3 + lane * 8, s3);
  }
}

// ---- fold from LDS levels1-3 + register B4 slice (k-sliced Chen product) ---
// Lane (i,j), slice k0: s1=S1[i], s2=S2[i][j], s3[k]=S3[i][j][k] full,
// s4[t][m]=S4[i][j][k0+t][m]. L = flat {S1|S2|S3} tile (584 floats).
__device__ __forceinline__ void fold_lds(const float* __restrict__ L,
                                         const float b4[2][D], float& s1,
                                         float& s2, float s3[D], float s4[2][D],
                                         int i, int j, int lane, int k0) {
  float b1i = L[i];
  float b1j = L[j];
  float sb1[D];
#pragma unroll
  for (int m = 0; m < D; ++m) sb1[m] = L[m];
  float b2own = L[OFF2 + lane];
  float b2row[D], b3own[D];
  *(float4*)&b2row[0] = *(const float4*)&L[OFF2 + j * 8];
  *(float4*)&b2row[4] = *(const float4*)&L[OFF2 + j * 8 + 4];
  *(float4*)&b3own[0] = *(const float4*)&L[OFF3 + lane * 8];
  *(float4*)&b3own[4] = *(const float4*)&L[OFF3 + lane * 8 + 4];

  // C4 = A4 + B4 + A3[i,j,k]B1[m] + A2[i,j]B2[k,m] + A1[i]B3[j,k,m]
#pragma unroll
  for (int t = 0; t < 2; ++t) {
    const int k = k0 + t;
    float b2k[D], b3k[D];
    *(float4*)&b2k[0] = *(const float4*)&L[OFF2 + k * 8];
    *(float4*)&b2k[4] = *(const float4*)&L[OFF2 + k * 8 + 4];
    *(float4*)&b3k[0] = *(const float4*)&L[OFF3 + (j * 8 + k) * 8];
    *(float4*)&b3k[4] = *(const float4*)&L[OFF3 + (j * 8 + k) * 8 + 4];
    float a3k = s3[k];
#pragma unroll
    for (int m = 0; m < D; ++m) {
      float v = __builtin_fmaf(a3k, sb1[m], s4[t][m] + b4[t][m]);
      v = __builtin_fmaf(s2, b2k[m], v);
      s4[t][m] = __builtin_fmaf(s1, b3k[m], v);
    }
  }
  // C3 = A3 + B3 + A1[i]B2[j,k] + A2[i,j]B1[k]
#pragma unroll
  for (int k = 0; k < D; ++k) {
    float v = __builtin_fmaf(s1, b2row[k], s3[k] + b3own[k]);
    s3[k] = __builtin_fmaf(s2, sb1[k], v);
  }
  s2 = s2 + b2own + s1 * b1j;
  s1 = s1 + b1i;
}

// Init state from sig0 at base, fold sigs 1..nsig-1. One sync per fold.
// (R9 shape - the only fold shape that keeps sane VGPR allocation.)
__device__ __forceinline__ void staged_folds(const float* __restrict__ base,
                                             int nsig, float (*lds13)[592],
                                             int tid, int i, int j, int lane,
                                             int k0, float& s1, float& s2,
                                             float s3[D], float s4[2][D]) {
  s1 = base[i];
  s2 = base[OFF2 + lane];
  load8(base + OFF3 + lane * 8, s3);
  load8(base + OFF4 + lane * 64 + k0 * 8, s4[0]);
  load8(base + OFF4 + lane * 64 + (k0 + 1) * 8, s4[1]);

  const float* __restrict__ B1p = base + (size_t)SIG_STRIDE;
  float b4cur[2][D];
  load8(B1p + OFF4 + lane * 64 + k0 * 8, b4cur[0]);
  load8(B1p + OFF4 + lane * 64 + (k0 + 1) * 8, b4cur[1]);
  if (tid < N13F4) {
    float4 sv = *(const float4*)(B1p + tid * 4);
    *(float4*)&lds13[1][tid * 4] = sv;
  }
  __syncthreads();

#pragma unroll 1
  for (int c = 1; c < nsig; ++c) {
    const bool more = (c + 1 < nsig);
    const float* __restrict__ Bn = base + (size_t)(c + 1) * SIG_STRIDE;
    float4 svn;
    float b4n[2][D];
    if (more) {
      if (tid < N13F4) svn = *(const float4*)(Bn + tid * 4);
      load8(Bn + OFF4 + lane * 64 + k0 * 8, b4n[0]);
      load8(Bn + OFF4 + lane * 64 + (k0 + 1) * 8, b4n[1]);
    }

    fold_lds(lds13[c & 1], b4cur, s1, s2, s3, s4, i, j, lane, k0);

    if (more) {
      if (tid < N13F4) *(float4*)&lds13[(c + 1) & 1][tid * 4] = svn;
#pragma unroll
      for (int t = 0; t < 2; ++t)
#pragma unroll
        for (int m = 0; m < D; ++m) b4cur[t][m] = b4n[t][m];
    }
    __syncthreads();
  }
}

// ------ Kernel 2: block bb folds the 8 chunk sigs of batch bb -> d_out ------
__global__ __launch_bounds__(256) void sig_fold8f(const float* __restrict__ ws,
                                                  float* __restrict__ out) {
  __shared__ alignas(16) float lds13[2][592];
  const int tid  = threadIdx.x;
  const int q    = tid >> 6;  // k-slice wave 0..3
  const int lane = tid & 63;
  const int bb = blockIdx.x;
  const int i = lane >> 3;
  const int j = lane & 7;
  const int k0 = q * 2;

  const float* __restrict__ base = ws + (size_t)bb * NCHUNK * SIG_STRIDE;

  float s1, s2, s3[D], s4[2][D];
  staged_folds(base, NCHUNK, lds13, tid, i, j, lane, k0, s1, s2, s3, s4);

  // d_out: S1 (32x8) | S2 (32x64) | S3 (32x512) | S4 (32x4096)
  if (q == 0) {
    if (j == 0) out[bb * 8 + i] = s1;
    out[256 + bb * 64 + lane] = s2;
    store8(out + 2304 + bb * 512 + lane * 8, s3);
  }
  store8(out + 18688 + bb * 4096 + lane * 64 + k0 * 8, s4[0]);
  store8(out + 18688 + bb * 4096 + lane * 64 + (k0 + 1) * 8, s4[1]);
}

extern "C" void kernel_launch(void* const* d_in, const int* in_sizes, int n_in,
                              void* d_out, int out_size, void* d_ws, size_t ws_size,
                              hipStream_t stream) {
  const float* path = (const float*)d_in[0];
  // d_in[1] = depth (==4), compile-time specialized.
  float* out = (float*)d_out;
  float* ws  = (float*)d_ws;  // 32*8*4680*4 = 4.8 MB used

  // 32 batches x 8 chunks = 256 blocks (4 q-waves each), 128 incs per chunk
  sig_chunk128<<<dim3(256), dim3(256), 0, stream>>>(path, ws);
  // 32 batches = 32 blocks; R9-shape staged fold over 8 sigs
  sig_fold8f<<<dim3(BATCH), dim3(256), 0, stream>>>(ws, out);
}